// Round 2
// baseline (165.548 us; speedup 1.0000x reference)
//
#include <hip/hip_runtime.h>

#define B_   16
#define NT_  4096
#define D_   512
#define CHUNK 256

typedef float f4 __attribute__((ext_vector_type(4)));

// ---------------------------------------------------------------------------
// Kernel 1: stable compaction of valid tokens per batch row + meta.
// grid = B_*16 blocks (one per (row, 256-chunk)), 256 threads.
// Robust to any validity pattern (doesn't assume prefix validity).
// (unchanged from verified version)
// ---------------------------------------------------------------------------
__global__ __launch_bounds__(256) void compact_kernel(const int* __restrict__ text,
                                                      int* __restrict__ tok,
                                                      int* __restrict__ meta) {
    const int b = blockIdx.x >> 4;   // 16 chunks per row
    const int c = blockIdx.x & 15;
    const int t = threadIdx.x;
    const int lane = t & 63;
    const int wid  = t >> 6;
    const int* row = text + b * NT_;

    // 1) count valid elements in preceding region [0, c*CHUNK)
    int pre = 0;
    for (int i = t; i < c * CHUNK; i += 256) pre += (row[i] >= 0) ? 1 : 0;
    #pragma unroll
    for (int off = 32; off > 0; off >>= 1) pre += __shfl_down(pre, off, 64);
    __shared__ int s_pre[4];
    if (lane == 0) s_pre[wid] = pre;
    __syncthreads();
    const int chunk_base = s_pre[0] + s_pre[1] + s_pre[2] + s_pre[3];

    // 2) own element: wave inclusive scan of predicate
    const int v = row[c * CHUNK + t];
    const int pred = (v >= 0) ? 1 : 0;
    int x = pred;
    #pragma unroll
    for (int off = 1; off < 64; off <<= 1) {
        int y = __shfl_up(x, off, 64);
        if (lane >= off) x += y;
    }
    __shared__ int s_wsum[4];
    if (lane == 63) s_wsum[wid] = x;
    __syncthreads();
    int woff = 0;
    for (int w = 0; w < wid; ++w) woff += s_wsum[w];

    if (pred) tok[b * NT_ + chunk_base + woff + (x - pred)] = v + 1;

    // 3) last chunk's last thread has the row total -> meta
    if (c == 15 && t == 255) {
        const int L  = chunk_base + woff + x;
        const int Ls = (L > 0) ? L : 1;
        const int base = NT_ / Ls;
        const int rem  = NT_ % Ls;
        meta[b * 4 + 0] = L;
        meta[b * 4 + 1] = base;
        meta[b * 4 + 2] = rem;
        meta[b * 4 + 3] = (Ls - rem) * base;   // boundary
    }
}

// ---------------------------------------------------------------------------
// Kernel 2 (fused map+expand): each block owns 16 consecutive output rows
// (16 x 512 floats = 32 KB). Threads 0..15 compute the source token index
// (the two integer divisions) into LDS; then all 256 threads stream the
// emb rows to the output.
// A/B vs round 1: PLAIN stores (nt reverted), and all 8 gather loads are
// issued as an explicit statically-indexed batch before the 8 stores so
// 8 loads/thread are in flight (latency hiding without relying on the
// scheduler's hoisting across the store in the same iteration).
// grid = B_*NT_/16 = 4096 blocks, 256 threads.
// ---------------------------------------------------------------------------
__global__ __launch_bounds__(256) void expand_fused(const f4* __restrict__ emb,
                                                    const int* __restrict__ tok,
                                                    const int* __restrict__ meta,
                                                    f4* __restrict__ out) {
    const int t     = threadIdx.x;
    const int pidx0 = blockIdx.x << 4;          // first (b,p) row of this block
    const int b     = pidx0 >> 12;              // NT_ = 4096 rows per batch

    __shared__ int s_tok[16];
    if (t < 16) {
        const int p = (pidx0 & (NT_ - 1)) + t;
        const int L = meta[b * 4 + 0];
        int tkn = -1;                           // -1 => write zeros (L == 0 row)
        if (L > 0) {
            const int base     = meta[b * 4 + 1];
            const int rem      = meta[b * 4 + 2];
            const int boundary = meta[b * 4 + 3];
            const int j = (p < boundary) ? (p / base)
                                         : ((L - rem) + (p - boundary) / (base + 1));
            tkn = tok[b * NT_ + j];             // already shifted (+1) by compact
        }
        s_tok[t] = tkn;
    }
    __syncthreads();

    const size_t obase = (size_t)pidx0 * (D_ / 4);   // in float4 units

    // phase 1: issue all 8 gathers (independent, statically indexed => regs)
    f4 v[8];
    #pragma unroll
    for (int k = 0; k < 8; ++k) {
        const int f   = (k << 8) + t;           // 0..2047 float4 within block
        const int tkn = s_tok[f >> 7];          // wave-uniform => LDS broadcast
        if (tkn < 0) {
            v[k] = (f4){0.f, 0.f, 0.f, 0.f};
        } else {
            v[k] = emb[(size_t)tkn * (D_ / 4) + (f & 127)];  // coalesced 1 KB/wave
        }
    }
    // phase 2: 8 coalesced streaming stores
    #pragma unroll
    for (int k = 0; k < 8; ++k) {
        out[obase + (k << 8) + t] = v[k];
    }
}

extern "C" void kernel_launch(void* const* d_in, const int* in_sizes, int n_in,
                              void* d_out, int out_size, void* d_ws, size_t ws_size,
                              hipStream_t stream) {
    const int*   text = (const int*)d_in[0];     // (B, NT) int
    // d_in[1] = seq_len scalar (== 4096, compile-time constant here)
    const float* emb  = (const float*)d_in[2];   // (V+1, D) f32
    f4*          out  = (f4*)d_out;              // (B, NT, D) f32

    int* tok  = (int*)d_ws;                      // B_*NT_ ints
    int* meta = tok + B_ * NT_;                  // B_*4 ints

    compact_kernel<<<B_ * 16, 256, 0, stream>>>(text, tok, meta);
    expand_fused<<<(B_ * NT_) / 16, 256, 0, stream>>>(
        (const f4*)emb, tok, meta, out);
}

// Round 3
// 155.974 us; speedup vs baseline: 1.0614x; 1.0614x over previous
//
#include <hip/hip_runtime.h>

#define B_   16
#define NT_  4096
#define D_   512

typedef float f4 __attribute__((ext_vector_type(4)));

// ---------------------------------------------------------------------------
// Single fused kernel: per-block stable-compaction index + gather-expand.
// grid = B_*NT_/16 = 4096 blocks x 256 threads. Block i owns 16 consecutive
// output rows (all within one batch row b). No workspace, no inter-kernel
// dependencies.
//
// Phase 1: thread t counts valid tokens in strip [t*16, t*16+16) of text row b
//          (row = 16 KB, L2-resident: 256 blocks share each row). Block-wide
//          inclusive scan over the 256 strip counts -> s_pref[], total L.
// Phase 2: 16 leader threads compute j(p) (the two integer divisions of the
//          even-stretch mapping), binary-search s_pref for the strip holding
//          rank j, walk <=16 elements to the j-th valid token -> s_tok[16].
// Phase 3: all 256 threads stream 16 rows x 512 floats: coalesced 1KB/wave emb
//          gathers (L2-hot, 5.2 MB table) + non-temporal stores (keep L2 for
//          emb; nt was the best-measured store flavor, round-1 A/B).
// ---------------------------------------------------------------------------
__global__ __launch_bounds__(256) void fused_all(const int* __restrict__ text,
                                                 const f4* __restrict__ emb,
                                                 f4* __restrict__ out) {
    const int t     = threadIdx.x;
    const int lane  = t & 63;
    const int wid   = t >> 6;
    const int pidx0 = blockIdx.x << 4;          // first output row of block
    const int b     = pidx0 >> 12;              // NT_ = 4096 rows per batch
    const int* row  = text + b * NT_;

    // ---- phase 1: strip counts + block scan --------------------------------
    int cnt = 0;
    #pragma unroll
    for (int k = 0; k < 16; ++k) cnt += (row[t * 16 + k] >= 0) ? 1 : 0;

    int x = cnt;                                 // wave inclusive scan
    #pragma unroll
    for (int off = 1; off < 64; off <<= 1) {
        int y = __shfl_up(x, off, 64);
        if (lane >= off) x += y;
    }
    __shared__ int s_wsum[4];
    if (lane == 63) s_wsum[wid] = x;
    __syncthreads();
    int woff = 0;
    for (int w = 0; w < wid; ++w) woff += s_wsum[w];
    const int L = s_wsum[0] + s_wsum[1] + s_wsum[2] + s_wsum[3];

    __shared__ int s_pref[256];                  // inclusive prefix over strips
    s_pref[t] = woff + x;
    __syncthreads();

    // ---- phase 2: leaders resolve their token ------------------------------
    __shared__ int s_tok[16];
    if (t < 16) {
        int tkn = -1;                            // -1 => write zeros (L == 0)
        if (L > 0) {
            const int base     = NT_ / L;
            const int rem      = NT_ % L;
            const int boundary = (L - rem) * base;
            const int p = (pidx0 & (NT_ - 1)) + t;
            const int j = (p < boundary) ? (p / base)
                                         : ((L - rem) + (p - boundary) / (base + 1));
            // smallest s with s_pref[s] > j  (exists: s_pref[255] = L > j)
            int lo = 0, hi = 255;
            while (lo < hi) {
                const int mid = (lo + hi) >> 1;
                if (s_pref[mid] > j) hi = mid; else lo = mid + 1;
            }
            const int s = lo;
            int r = j - ((s > 0) ? s_pref[s - 1] : 0);   // rank within strip
            const int* strip = row + s * 16;
            for (int k = 0; k < 16; ++k) {
                const int v = strip[k];
                if (v >= 0) {
                    if (r == 0) { tkn = v + 1; break; }
                    --r;
                }
            }
        }
        s_tok[t] = tkn;
    }
    __syncthreads();

    // ---- phase 3: streaming expand (best-measured variant: nt stores) -----
    const size_t obase = (size_t)pidx0 * (D_ / 4);       // float4 units
    #pragma unroll
    for (int k = 0; k < 8; ++k) {
        const int f   = (k << 8) + t;            // 0..2047 float4 within block
        const int tkn = s_tok[f >> 7];           // wave-uniform => LDS broadcast
        f4 v;
        if (tkn < 0) {
            v = (f4){0.f, 0.f, 0.f, 0.f};
        } else {
            v = emb[(size_t)tkn * (D_ / 4) + (f & 127)]; // coalesced 1 KB/wave
        }
        __builtin_nontemporal_store(v, &out[obase + f]); // bypass L2
    }
}

extern "C" void kernel_launch(void* const* d_in, const int* in_sizes, int n_in,
                              void* d_out, int out_size, void* d_ws, size_t ws_size,
                              hipStream_t stream) {
    const int*   text = (const int*)d_in[0];     // (B, NT) int
    // d_in[1] = seq_len scalar (== 4096, compile-time constant here)
    const float* emb  = (const float*)d_in[2];   // (V+1, D) f32
    f4*          out  = (f4*)d_out;              // (B, NT, D) f32

    fused_all<<<(B_ * NT_) / 16, 256, 0, stream>>>(
        text, (const f4*)emb, out);
}